// Round 1
// baseline (812.889 us; speedup 1.0000x reference)
//
#include <hip/hip_runtime.h>
#include <hip/hip_cooperative_groups.h>
#include <hip/hip_bf16.h>

namespace cg = cooperative_groups;

// ---------------------------------------------------------------------------
// Problem: MPS contraction, N=512 sites, D_PHY=4, D_BOND=128, VOC=1024.
//   Aq = qr(A.reshape(4096,4)).Q ; M_v = Aq_v^H Aq_v ; Ms = M[tokens]
//   S0 = site(ones(1,1), B0, Ms[0]);  S_{t} = site(S, Bm[t-1], Ms[t]) t=1..510
//   out = site(S, Bl, Ms[511])  -> single complex64 scalar.
// Site map is strictly linear in S; magnitudes contract ~1e-3/site
// (trace M_v ~ 1/256), so S underflows to EXACT zero after ~20 sites.
// We therefore run the faithful computation with an exact all-zero early exit.
// ---------------------------------------------------------------------------

__device__ __forceinline__ float2 cfma(float2 a, float2 b, float2 acc) {
    // acc + a*b
    acc.x = fmaf(a.x, b.x, fmaf(-a.y, b.y, acc.x));
    acc.y = fmaf(a.x, b.y, fmaf( a.y, b.x, acc.y));
    return acc;
}
__device__ __forceinline__ float2 cfmac(float2 a, float2 b, float2 acc) {
    // acc + conj(a)*b
    acc.x = fmaf(a.x, b.x, fmaf( a.y, b.y, acc.x));
    acc.y = fmaf(a.x, b.y, fmaf(-a.y, b.x, acc.y));
    return acc;
}

__device__ __forceinline__ double2 d2mul(double2 a, double2 b) {
    return make_double2(a.x*b.x - a.y*b.y, a.x*b.y + a.y*b.x);
}
__device__ __forceinline__ double2 d2conj(double2 a) { return make_double2(a.x, -a.y); }

// block reduction over 512 threads (8 waves), deterministic
__device__ double2 qr_blk_red(double2 v, double2* red) {
    for (int off = 32; off; off >>= 1) {
        v.x += __shfl_down(v.x, off, 64);
        v.y += __shfl_down(v.y, off, 64);
    }
    const int wid = threadIdx.x >> 6, lane = threadIdx.x & 63;
    __syncthreads();                 // protect red[] from previous use
    if (lane == 0) red[wid] = v;
    __syncthreads();
    double2 r = make_double2(0.0, 0.0);
    for (int w = 0; w < 8; ++w) { r.x += red[w].x; r.y += red[w].y; }
    return r;
}

// ---------------------------------------------------------------------------
// Kernel 1: Householder QR of A (4096 x 4 complex), LAPACK cgeqrf/cungqr
// convention (clarfg: beta real, beta = -sign(Re(alpha))*|.|). The phase
// convention matters: M_v = Q_v^H Q_v is NOT invariant under per-column
// phase changes of Q. One workgroup, 512 threads, 8 rows/thread.
// ---------------------------------------------------------------------------
__global__ __launch_bounds__(512) void qr_kernel(const float* __restrict__ a_re,
                                                 const float* __restrict__ a_im,
                                                 float2* __restrict__ Q)
{
    const int t = threadIdx.x;
    __shared__ double2 red[8];
    __shared__ double2 bc;

    float2 a[8][4];
    for (int i = 0; i < 8; ++i) {
        int r = t + 512 * i;
        for (int j = 0; j < 4; ++j)
            a[i][j] = make_float2(a_re[r*4 + j], a_im[r*4 + j]);
    }
    double2 tau[4];

    for (int k = 0; k < 4; ++k) {
        if (t == k) bc = make_double2((double)a[0][k].x, (double)a[0][k].y);
        __syncthreads();
        const double ar = bc.x, ai = bc.y;

        double xn = 0.0;
        for (int i = 0; i < 8; ++i) {
            int r = t + 512 * i;
            if (r > k) xn += (double)a[i][k].x * a[i][k].x + (double)a[i][k].y * a[i][k].y;
        }
        xn = qr_blk_red(make_double2(xn, 0.0), red).x;

        double2 tk, scale;
        if (xn == 0.0 && ai == 0.0) {
            tk = make_double2(0.0, 0.0);
            scale = make_double2(0.0, 0.0);
        } else {
            double nrm = sqrt(ar*ar + ai*ai + xn);
            double beta = (ar >= 0.0) ? -nrm : nrm;       // clarfg sign rule
            tk = make_double2((beta - ar) / beta, -ai / beta);
            double dr = ar - beta, di = ai;
            double dd = dr*dr + di*di;
            scale = make_double2(dr / dd, -di / dd);      // 1/(alpha-beta)
        }
        tau[k] = tk;

        // form v in column k (v=0 above k, 1 at k, x*scale below)
        for (int i = 0; i < 8; ++i) {
            int r = t + 512 * i;
            if (r == k) a[i][k] = make_float2(1.f, 0.f);
            else if (r > k) {
                double2 v = d2mul(make_double2(a[i][k].x, a[i][k].y), scale);
                a[i][k] = make_float2((float)v.x, (float)v.y);
            } else a[i][k] = make_float2(0.f, 0.f);
        }
        __syncthreads();

        // trailing update: A[:,j] -= conj(tau) * v * (v^H A[:,j])
        for (int j = k + 1; j < 4; ++j) {
            double2 w = make_double2(0.0, 0.0);
            for (int i = 0; i < 8; ++i) {
                double2 vv = make_double2(a[i][k].x, a[i][k].y);
                double2 aa = make_double2(a[i][j].x, a[i][j].y);
                double2 m = d2mul(d2conj(vv), aa);
                w.x += m.x; w.y += m.y;
            }
            w = qr_blk_red(w, red);
            double2 cw = d2mul(d2conj(tk), w);
            for (int i = 0; i < 8; ++i) {
                double2 vv = make_double2(a[i][k].x, a[i][k].y);
                double2 upd = d2mul(cw, vv);
                a[i][j] = make_float2((float)((double)a[i][j].x - upd.x),
                                      (float)((double)a[i][j].y - upd.y));
            }
        }
    }

    // cungqr: Q = H1 H2 H3 H4 * I(4096x4); apply H = I - tau v v^H, k=3..0
    float2 q[8][4];
    for (int i = 0; i < 8; ++i) {
        int r = t + 512 * i;
        for (int j = 0; j < 4; ++j)
            q[i][j] = make_float2((r == j) ? 1.f : 0.f, 0.f);
    }
    for (int k = 3; k >= 0; --k) {
        for (int j = k; j < 4; ++j) {
            double2 w = make_double2(0.0, 0.0);
            for (int i = 0; i < 8; ++i) {
                double2 vv = make_double2(a[i][k].x, a[i][k].y);
                double2 qq = make_double2(q[i][j].x, q[i][j].y);
                double2 m = d2mul(d2conj(vv), qq);
                w.x += m.x; w.y += m.y;
            }
            w = qr_blk_red(w, red);
            double2 cw = d2mul(tau[k], w);
            for (int i = 0; i < 8; ++i) {
                double2 vv = make_double2(a[i][k].x, a[i][k].y);
                double2 upd = d2mul(cw, vv);
                q[i][j] = make_float2((float)((double)q[i][j].x - upd.x),
                                      (float)((double)q[i][j].y - upd.y));
            }
        }
    }
    for (int i = 0; i < 8; ++i) {
        int r = t + 512 * i;
        for (int j = 0; j < 4; ++j) Q[r*4 + j] = q[i][j];
    }
}

// ---------------------------------------------------------------------------
// Kernel 2: Ms[t][j][k] = sum_i conj(Q[4v+i,j]) Q[4v+i,k], v=tokens[t].
// Also zeroes the per-site liveness flags (re-zeroed every replay).
// ---------------------------------------------------------------------------
__global__ __launch_bounds__(256) void ms_kernel(const float2* __restrict__ Q,
                                                 const int* __restrict__ tokens,
                                                 float2* __restrict__ Ms,
                                                 unsigned int* __restrict__ flags)
{
    const int idx = blockIdx.x * 256 + threadIdx.x;   // 32 blocks -> 8192
    if (idx < 8192) {
        const int ti = idx >> 4, jk = idx & 15, j = jk >> 2, kk = jk & 3;
        const int v = tokens[ti];
        float2 s = make_float2(0.f, 0.f);
        for (int i = 0; i < 4; ++i) {
            float2 q1 = Q[(v*4 + i)*4 + j];
            float2 q2 = Q[(v*4 + i)*4 + kk];
            s.x += q1.x*q2.x + q1.y*q2.y;     // conj(q1)*q2
            s.y += q1.x*q2.y - q1.y*q2.x;
        }
        Ms[idx] = s;
    }
    if (idx < 512) flags[idx] = 0u;
}

// ---------------------------------------------------------------------------
// Kernel 3: site 0.  S1[r,c] = sum_{p,q} conj(B0[p,r]) M0[p,q] B0[q,c].
// Stored TRANSPOSED: S0[c*128 + r] = S1[r][c]  (so scan reads are coalesced).
// ---------------------------------------------------------------------------
__global__ __launch_bounds__(256) void s1_kernel(const float* __restrict__ b0_re,
                                                 const float* __restrict__ b0_im,
                                                 const float2* __restrict__ Ms,
                                                 float2* __restrict__ S0)
{
    const int idx = blockIdx.x * 256 + threadIdx.x;   // 64 blocks -> 16384
    const int c = idx >> 7, r = idx & 127;
    float2 brr[4], bcc[4];
    for (int p = 0; p < 4; ++p) {
        brr[p] = make_float2(b0_re[p*128 + r], b0_im[p*128 + r]);
        bcc[p] = make_float2(b0_re[p*128 + c], b0_im[p*128 + c]);
    }
    float2 acc = make_float2(0.f, 0.f);
    for (int p = 0; p < 4; ++p) {
        float2 tp = make_float2(0.f, 0.f);
        for (int q = 0; q < 4; ++q) {
            float2 m = Ms[p*4 + q];
            tp = cfma(m, bcc[q], tp);
        }
        acc = cfmac(brr[p], tp, acc);
    }
    S0[c*128 + r] = acc;
}

// ---------------------------------------------------------------------------
// Kernel 4: cooperative scan over middle sites t=1..510 + final site.
// 128 wgs x 256 threads; wg handles output column c (XCD-grouped mapping).
// Per site: C[p][b] = sum_q M[p,q] B[q,b,c]   (LDS)
//           U[p][a] = sum_b S[a,b] C[p][b]     (transposed-S coalesced reads)
//           out[r]  = sum_{pa} conj(B[p,a,r]) U[pa]
// One grid.sync per site; exact early exit when new S is identically zero.
// ---------------------------------------------------------------------------
__global__ __launch_bounds__(256) void scan_kernel(
    const float* __restrict__ bm_re, const float* __restrict__ bm_im,
    const float* __restrict__ bl_re, const float* __restrict__ bl_im,
    const float2* __restrict__ Ms,
    float2* SbufA, float2* SbufB,
    unsigned int* flags, float* out, int out_size)
{
    cg::grid_group grid = cg::this_grid();
    const int tid = threadIdx.x;
    const int bid = blockIdx.x;
    const int c = ((bid & 7) << 4) | (bid >> 3);   // same-XCD wgs -> adjacent c

    __shared__ float2 Clds[4][128];
    __shared__ float2 Upart[2][512];
    __shared__ float2 U[512];
    __shared__ float2 red2[2][128];
    __shared__ float2 fred[4];

    float2* Sread = SbufA;
    float2* Swrite = SbufB;
    bool dead = false;

    const int a = tid & 127;
    const int h = tid >> 7;

    for (int t = 1; t <= 510; ++t) {
        const float2* Mt = Ms + t * 16;
        const float* br = bm_re + (size_t)(t - 1) * 65536;
        const float* bi = bm_im + (size_t)(t - 1) * 65536;

        // ---- C[p][b] (2 entries per thread)
        for (int e = 0; e < 2; ++e) {
            int pb = tid + e * 256;
            int p = pb >> 7, b = pb & 127;
            float2 acc = make_float2(0.f, 0.f);
            for (int q = 0; q < 4; ++q) {
                float2 m = Mt[p*4 + q];
                float2 bqv = make_float2(br[(q*128 + b)*128 + c],
                                         bi[(q*128 + b)*128 + c]);
                acc = cfma(m, bqv, acc);
            }
            Clds[p][b] = acc;
        }
        __syncthreads();

        // ---- U[p][a]: this half sums b in [h*64, h*64+64)
        float2 u0 = make_float2(0,0), u1 = u0, u2 = u0, u3 = u0;
        #pragma unroll 4
        for (int b = h * 64; b < h * 64 + 64; ++b) {
            float2 s = Sread[b * 128 + a];       // = S[a][b], coalesced on a
            u0 = cfma(s, Clds[0][b], u0);
            u1 = cfma(s, Clds[1][b], u1);
            u2 = cfma(s, Clds[2][b], u2);
            u3 = cfma(s, Clds[3][b], u3);
        }
        Upart[h][0*128 + a] = u0;
        Upart[h][1*128 + a] = u1;
        Upart[h][2*128 + a] = u2;
        Upart[h][3*128 + a] = u3;
        __syncthreads();
        for (int e = 0; e < 2; ++e) {
            int pa = tid + e * 256;
            float2 x = Upart[0][pa], y = Upart[1][pa];
            U[pa] = make_float2(x.x + y.x, x.y + y.y);
        }
        __syncthreads();

        // ---- out[r] : this half sums pa in [h*256, h*256+256)
        const int r = a;
        float2 o0 = make_float2(0,0), o1 = o0;
        #pragma unroll 4
        for (int pa = h * 256; pa < h * 256 + 256; pa += 2) {
            float2 b1 = make_float2(br[pa*128 + r],     bi[pa*128 + r]);
            float2 b2 = make_float2(br[(pa+1)*128 + r], bi[(pa+1)*128 + r]);
            o0 = cfmac(b1, U[pa],     o0);
            o1 = cfmac(b2, U[pa + 1], o1);
        }
        o0.x += o1.x; o0.y += o1.y;
        red2[h][r] = o0;
        __syncthreads();
        if (h == 0) {
            float2 fin = make_float2(red2[0][r].x + red2[1][r].x,
                                     red2[0][r].y + red2[1][r].y);
            Swrite[c * 128 + r] = fin;           // transposed store, coalesced
            int nz = (fin.x != 0.f) || (fin.y != 0.f);
            unsigned long long msk = __ballot(nz);
            if ((tid & 63) == 0 && msk != 0ULL) atomicOr(&flags[t], 1u);
        }
        __threadfence();
        grid.sync();
        unsigned f = __hip_atomic_load(&flags[t], __ATOMIC_ACQUIRE,
                                       __HIP_MEMORY_SCOPE_AGENT);
        if (f == 0u) { dead = true; break; }     // uniform across grid: exact exit
        float2* tmp = Sread; Sread = Swrite; Swrite = tmp;
    }

    if (dead) {
        if (bid == 0 && tid == 0) {
            out[0] = 0.f;
            if (out_size > 1) out[1] = 0.f;
        }
        return;
    }
    if (bid != 0) return;

    // ---- final site: Bl (4,128,1), Ms[511]; S = Sread (transposed storage)
    const float2* Mt = Ms + 511 * 16;
    {   // t1[q][a] = sum_b S[a,b] * Bl[q,b]; thread covers q = h and h+2
        float2 acc0 = make_float2(0,0), acc1 = acc0;
        for (int b = 0; b < 128; ++b) {
            float2 s = Sread[b * 128 + a];
            float2 bl0 = make_float2(bl_re[h*128 + b],       bl_im[h*128 + b]);
            float2 bl1 = make_float2(bl_re[(h+2)*128 + b],   bl_im[(h+2)*128 + b]);
            acc0 = cfma(s, bl0, acc0);
            acc1 = cfma(s, bl1, acc1);
        }
        Clds[h][a]     = acc0;    // reuse Clds as t1[4][128]
        Clds[h + 2][a] = acc1;
    }
    __syncthreads();
    float2 tot = make_float2(0,0);
    for (int pp = 0; pp < 2; ++pp) {
        int p = h + pp * 2;
        float2 tp = make_float2(0,0);
        for (int q = 0; q < 4; ++q) tp = cfma(Mt[p*4 + q], Clds[q][a], tp);
        float2 blv = make_float2(bl_re[p*128 + a], bl_im[p*128 + a]);
        tot = cfmac(blv, tp, tot);
    }
    for (int off = 32; off; off >>= 1) {
        tot.x += __shfl_down(tot.x, off, 64);
        tot.y += __shfl_down(tot.y, off, 64);
    }
    if ((tid & 63) == 0) fred[tid >> 6] = tot;
    __syncthreads();
    if (tid == 0) {
        float2 s = make_float2(0,0);
        for (int w = 0; w < 4; ++w) { s.x += fred[w].x; s.y += fred[w].y; }
        out[0] = s.x;
        if (out_size > 1) out[1] = s.y;
    }
}

// ---------------------------------------------------------------------------
extern "C" void kernel_launch(void* const* d_in, const int* in_sizes, int n_in,
                              void* d_out, int out_size, void* d_ws, size_t ws_size,
                              hipStream_t stream)
{
    const float* a_re  = (const float*)d_in[0];
    const float* a_im  = (const float*)d_in[1];
    const float* b0_re = (const float*)d_in[2];
    const float* b0_im = (const float*)d_in[3];
    const float* bm_re = (const float*)d_in[4];
    const float* bm_im = (const float*)d_in[5];
    const float* bl_re = (const float*)d_in[6];
    const float* bl_im = (const float*)d_in[7];
    const int*  tokens = (const int*)d_in[8];

    char* ws = (char*)d_ws;
    float2* Q    = (float2*)(ws);                   // 131072 B
    float2* Ms   = (float2*)(ws + 131072);          //  65536 B
    float2* S0   = (float2*)(ws + 196608);          // 131072 B
    float2* S1b  = (float2*)(ws + 327680);          // 131072 B
    unsigned int* flags = (unsigned int*)(ws + 458752); // 2048 B

    qr_kernel<<<dim3(1), dim3(512), 0, stream>>>(a_re, a_im, Q);
    ms_kernel<<<dim3(32), dim3(256), 0, stream>>>((const float2*)Q, tokens, Ms, flags);
    s1_kernel<<<dim3(64), dim3(256), 0, stream>>>(b0_re, b0_im, (const float2*)Ms, S0);

    float* outf = (float*)d_out;
    int osz = out_size;
    void* args[] = {
        (void*)&bm_re, (void*)&bm_im, (void*)&bl_re, (void*)&bl_im,
        (void*)&Ms, (void*)&S0, (void*)&S1b, (void*)&flags, (void*)&outf, (void*)&osz
    };
    hipLaunchCooperativeKernel((const void*)scan_kernel, dim3(128), dim3(256),
                               args, 0, stream);
}

// Round 2
// 461.776 us; speedup vs baseline: 1.7604x; 1.7604x over previous
//
#include <hip/hip_runtime.h>
#include <hip/hip_cooperative_groups.h>
#include <hip/hip_bf16.h>

// ---------------------------------------------------------------------------
// MPS contraction, N=512 sites, D_PHY=4, D_BOND=128, VOC=1024.
// Faithful computation with EXACT all-zero early exit (state underflows to
// exact 0 after ~20 sites; site map is linear, so remaining sites stay 0).
// Round-2 change: cg::grid.sync + threadfence + separate flag (3 device-scope
// round trips/site, ~36 us/site) replaced by ONE fused release-RMW barrier
// carrying the liveness bit, tight s_sleep spin, one acquire fence.
// ---------------------------------------------------------------------------

__device__ __forceinline__ float2 cfma(float2 a, float2 b, float2 acc) {
    acc.x = fmaf(a.x, b.x, fmaf(-a.y, b.y, acc.x));
    acc.y = fmaf(a.x, b.y, fmaf( a.y, b.x, acc.y));
    return acc;
}
__device__ __forceinline__ float2 cfmac(float2 a, float2 b, float2 acc) {
    // acc + conj(a)*b
    acc.x = fmaf(a.x, b.x, fmaf( a.y, b.y, acc.x));
    acc.y = fmaf(a.x, b.y, fmaf(-a.y, b.x, acc.y));
    return acc;
}

__device__ __forceinline__ double2 d2mul(double2 a, double2 b) {
    return make_double2(a.x*b.x - a.y*b.y, a.x*b.y + a.y*b.x);
}
__device__ __forceinline__ double2 d2conj(double2 a) { return make_double2(a.x, -a.y); }

// block reduction over 512 threads (8 waves), deterministic
__device__ double2 qr_blk_red(double2 v, double2* red) {
    for (int off = 32; off; off >>= 1) {
        v.x += __shfl_down(v.x, off, 64);
        v.y += __shfl_down(v.y, off, 64);
    }
    const int wid = threadIdx.x >> 6, lane = threadIdx.x & 63;
    __syncthreads();
    if (lane == 0) red[wid] = v;
    __syncthreads();
    double2 r = make_double2(0.0, 0.0);
    for (int w = 0; w < 8; ++w) { r.x += red[w].x; r.y += red[w].y; }
    return r;
}

// ---------------------------------------------------------------------------
// Kernel 1: Householder QR of A (4096 x 4 complex), LAPACK clarfg/cungqr
// convention (beta real, sign rule pins the column phases M depends on).
// ---------------------------------------------------------------------------
__global__ __launch_bounds__(512) void qr_kernel(const float* __restrict__ a_re,
                                                 const float* __restrict__ a_im,
                                                 float2* __restrict__ Q)
{
    const int t = threadIdx.x;
    __shared__ double2 red[8];
    __shared__ double2 bc;

    float2 a[8][4];
    for (int i = 0; i < 8; ++i) {
        int r = t + 512 * i;
        for (int j = 0; j < 4; ++j)
            a[i][j] = make_float2(a_re[r*4 + j], a_im[r*4 + j]);
    }
    double2 tau[4];

    for (int k = 0; k < 4; ++k) {
        if (t == k) bc = make_double2((double)a[0][k].x, (double)a[0][k].y);
        __syncthreads();
        const double ar = bc.x, ai = bc.y;

        double xn = 0.0;
        for (int i = 0; i < 8; ++i) {
            int r = t + 512 * i;
            if (r > k) xn += (double)a[i][k].x * a[i][k].x + (double)a[i][k].y * a[i][k].y;
        }
        xn = qr_blk_red(make_double2(xn, 0.0), red).x;

        double2 tk, scale;
        if (xn == 0.0 && ai == 0.0) {
            tk = make_double2(0.0, 0.0);
            scale = make_double2(0.0, 0.0);
        } else {
            double nrm = sqrt(ar*ar + ai*ai + xn);
            double beta = (ar >= 0.0) ? -nrm : nrm;       // clarfg sign rule
            tk = make_double2((beta - ar) / beta, -ai / beta);
            double dr = ar - beta, di = ai;
            double dd = dr*dr + di*di;
            scale = make_double2(dr / dd, -di / dd);      // 1/(alpha-beta)
        }
        tau[k] = tk;

        for (int i = 0; i < 8; ++i) {
            int r = t + 512 * i;
            if (r == k) a[i][k] = make_float2(1.f, 0.f);
            else if (r > k) {
                double2 v = d2mul(make_double2(a[i][k].x, a[i][k].y), scale);
                a[i][k] = make_float2((float)v.x, (float)v.y);
            } else a[i][k] = make_float2(0.f, 0.f);
        }
        __syncthreads();

        for (int j = k + 1; j < 4; ++j) {
            double2 w = make_double2(0.0, 0.0);
            for (int i = 0; i < 8; ++i) {
                double2 vv = make_double2(a[i][k].x, a[i][k].y);
                double2 aa = make_double2(a[i][j].x, a[i][j].y);
                double2 m = d2mul(d2conj(vv), aa);
                w.x += m.x; w.y += m.y;
            }
            w = qr_blk_red(w, red);
            double2 cw = d2mul(d2conj(tk), w);
            for (int i = 0; i < 8; ++i) {
                double2 vv = make_double2(a[i][k].x, a[i][k].y);
                double2 upd = d2mul(cw, vv);
                a[i][j] = make_float2((float)((double)a[i][j].x - upd.x),
                                      (float)((double)a[i][j].y - upd.y));
            }
        }
    }

    float2 q[8][4];
    for (int i = 0; i < 8; ++i) {
        int r = t + 512 * i;
        for (int j = 0; j < 4; ++j)
            q[i][j] = make_float2((r == j) ? 1.f : 0.f, 0.f);
    }
    for (int k = 3; k >= 0; --k) {
        for (int j = k; j < 4; ++j) {
            double2 w = make_double2(0.0, 0.0);
            for (int i = 0; i < 8; ++i) {
                double2 vv = make_double2(a[i][k].x, a[i][k].y);
                double2 qq = make_double2(q[i][j].x, q[i][j].y);
                double2 m = d2mul(d2conj(vv), qq);
                w.x += m.x; w.y += m.y;
            }
            w = qr_blk_red(w, red);
            double2 cw = d2mul(tau[k], w);
            for (int i = 0; i < 8; ++i) {
                double2 vv = make_double2(a[i][k].x, a[i][k].y);
                double2 upd = d2mul(cw, vv);
                q[i][j] = make_float2((float)((double)q[i][j].x - upd.x),
                                      (float)((double)q[i][j].y - upd.y));
            }
        }
    }
    for (int i = 0; i < 8; ++i) {
        int r = t + 512 * i;
        for (int j = 0; j < 4; ++j) Q[r*4 + j] = q[i][j];
    }
}

// ---------------------------------------------------------------------------
// Kernel 2: Ms[t][j][k] = sum_i conj(Q[4v+i,j]) Q[4v+i,k], v=tokens[t];
// zeroes the per-site barrier counters (fresh every replay).
// ---------------------------------------------------------------------------
__global__ __launch_bounds__(256) void ms_kernel(const float2* __restrict__ Q,
                                                 const int* __restrict__ tokens,
                                                 float2* __restrict__ Ms,
                                                 unsigned int* __restrict__ cnt)
{
    const int idx = blockIdx.x * 256 + threadIdx.x;   // 32 blocks -> 8192
    if (idx < 8192) {
        const int ti = idx >> 4, jk = idx & 15, j = jk >> 2, kk = jk & 3;
        const int v = tokens[ti];
        float2 s = make_float2(0.f, 0.f);
        for (int i = 0; i < 4; ++i) {
            float2 q1 = Q[(v*4 + i)*4 + j];
            float2 q2 = Q[(v*4 + i)*4 + kk];
            s.x += q1.x*q2.x + q1.y*q2.y;     // conj(q1)*q2
            s.y += q1.x*q2.y - q1.y*q2.x;
        }
        Ms[idx] = s;
    }
    if (idx < 512) cnt[idx] = 0u;
}

// ---------------------------------------------------------------------------
// Fused grid barrier + liveness for one site.
// Each wg adds 1 | (nz<<16) with RELEASE (flushes its XCD's dirty S lines);
// thread 0 spins until the count field == 128. The word is FINAL at that
// moment (every wg adds exactly once), so all wgs read identical liveness ->
// uniform break. One acquire fence afterwards makes released S visible.
// ---------------------------------------------------------------------------
#define NWG 128u
__device__ __forceinline__ bool site_barrier(unsigned int* addr,
                                             unsigned* nzw, int* live_lds, int tid)
{
    __syncthreads();                       // wg's S stores complete to L2
    if (tid == 0) {
        unsigned add = 1u | ((nzw[0] | nzw[1]) ? 0x10000u : 0u);
        __hip_atomic_fetch_add(addr, add, __ATOMIC_RELEASE, __HIP_MEMORY_SCOPE_AGENT);
        unsigned v;
        for (;;) {
            v = __hip_atomic_load(addr, __ATOMIC_RELAXED, __HIP_MEMORY_SCOPE_AGENT);
            if ((v & 0xffffu) >= NWG) break;
            __builtin_amdgcn_s_sleep(2);
        }
        *live_lds = (int)(v >> 16);
    }
    __syncthreads();
    __builtin_amdgcn_fence(__ATOMIC_ACQUIRE, "agent");
    return *live_lds != 0;
}

// ---------------------------------------------------------------------------
// Kernel 3: site 0 (folded) + cooperative scan t=1..510 + final site.
// 128 wgs x 256 threads; wg owns output column c (XCD-grouped mapping).
// ---------------------------------------------------------------------------
__global__ __launch_bounds__(256) void scan_kernel(
    const float* __restrict__ bm_re, const float* __restrict__ bm_im,
    const float* __restrict__ b0_re, const float* __restrict__ b0_im,
    const float* __restrict__ bl_re, const float* __restrict__ bl_im,
    const float2* __restrict__ Ms,
    float2* SbufA, float2* SbufB,
    unsigned int* cnt, float* out, int out_size)
{
    const int tid = threadIdx.x;
    const int bid = blockIdx.x;
    const int c = ((bid & 7) << 4) | (bid >> 3);   // same-XCD wgs -> adjacent c

    __shared__ float2 Clds[4][128];
    __shared__ float2 Upart[2][512];
    __shared__ float2 U[512];
    __shared__ float2 red2[2][128];
    __shared__ float2 fred[4];
    __shared__ unsigned nzw[2];
    __shared__ int live_lds;

    const int a = tid & 127;
    const int h = tid >> 7;

    float2* Sread = SbufA;
    float2* Swrite = SbufB;
    bool dead = false;

    // ---- site 0: this wg computes column c of S0 -> SbufA (transposed store)
    if (h == 0) {
        const int r = a;
        float2 brr[4], bcc[4];
        for (int p = 0; p < 4; ++p) {
            brr[p] = make_float2(b0_re[p*128 + r], b0_im[p*128 + r]);
            bcc[p] = make_float2(b0_re[p*128 + c], b0_im[p*128 + c]);
        }
        float2 acc = make_float2(0.f, 0.f);
        for (int p = 0; p < 4; ++p) {
            float2 tp = make_float2(0.f, 0.f);
            for (int q = 0; q < 4; ++q) tp = cfma(Ms[p*4 + q], bcc[q], tp);
            acc = cfmac(brr[p], tp, acc);
        }
        SbufA[c*128 + r] = acc;
        int nz = (acc.x != 0.f) || (acc.y != 0.f);
        unsigned long long m = __ballot(nz);
        if ((tid & 63) == 0) nzw[tid >> 6] = (m != 0ULL) ? 1u : 0u;
    }
    if (!site_barrier(&cnt[0], nzw, &live_lds, tid)) dead = true;

    if (!dead) {
        for (int t = 1; t <= 510; ++t) {
            const float2* Mt = Ms + t * 16;
            const float* br = bm_re + (size_t)(t - 1) * 65536;
            const float* bi = bm_im + (size_t)(t - 1) * 65536;

            // ---- C[p][b] = sum_q M[p,q] B[q,b,c]   (2 entries/thread)
            for (int e = 0; e < 2; ++e) {
                int pb = tid + e * 256;
                int p = pb >> 7, b = pb & 127;
                float2 acc = make_float2(0.f, 0.f);
                for (int q = 0; q < 4; ++q) {
                    float2 m = Mt[p*4 + q];
                    float2 bqv = make_float2(br[(q*128 + b)*128 + c],
                                             bi[(q*128 + b)*128 + c]);
                    acc = cfma(m, bqv, acc);
                }
                Clds[p][b] = acc;
            }
            __syncthreads();

            // ---- U[p][a] = sum_b S[a,b] C[p][b]; halves split b
            float2 u0 = make_float2(0,0), u1 = u0, u2 = u0, u3 = u0;
            #pragma unroll 4
            for (int b = h * 64; b < h * 64 + 64; ++b) {
                float2 s = Sread[b * 128 + a];     // coalesced on a
                u0 = cfma(s, Clds[0][b], u0);
                u1 = cfma(s, Clds[1][b], u1);
                u2 = cfma(s, Clds[2][b], u2);
                u3 = cfma(s, Clds[3][b], u3);
            }
            Upart[h][0*128 + a] = u0;
            Upart[h][1*128 + a] = u1;
            Upart[h][2*128 + a] = u2;
            Upart[h][3*128 + a] = u3;
            __syncthreads();
            for (int e = 0; e < 2; ++e) {
                int pa = tid + e * 256;
                float2 x = Upart[0][pa], y = Upart[1][pa];
                U[pa] = make_float2(x.x + y.x, x.y + y.y);
            }
            __syncthreads();

            // ---- out[r] = sum_pa conj(B[p,a,r]) U[pa]; halves split pa
            const int r = a;
            float2 o0 = make_float2(0,0), o1 = o0;
            #pragma unroll 4
            for (int pa = h * 256; pa < h * 256 + 256; pa += 2) {
                float2 b1 = make_float2(br[pa*128 + r],     bi[pa*128 + r]);
                float2 b2 = make_float2(br[(pa+1)*128 + r], bi[(pa+1)*128 + r]);
                o0 = cfmac(b1, U[pa],     o0);
                o1 = cfmac(b2, U[pa + 1], o1);
            }
            o0.x += o1.x; o0.y += o1.y;
            red2[h][r] = o0;
            __syncthreads();
            if (h == 0) {
                float2 fin = make_float2(red2[0][r].x + red2[1][r].x,
                                         red2[0][r].y + red2[1][r].y);
                Swrite[c * 128 + r] = fin;          // transposed, coalesced
                int nz = (fin.x != 0.f) || (fin.y != 0.f);
                unsigned long long m = __ballot(nz);
                if ((tid & 63) == 0) nzw[tid >> 6] = (m != 0ULL) ? 1u : 0u;
            }
            if (!site_barrier(&cnt[t], nzw, &live_lds, tid)) { dead = true; break; }
            float2* tmp = Sread; Sread = Swrite; Swrite = tmp;
        }
    }

    if (dead) {
        if (bid == 0 && tid == 0) {
            out[0] = 0.f;
            if (out_size > 1) out[1] = 0.f;
        }
        return;
    }
    if (bid != 0) return;

    // ---- final site: Bl (4,128,1), Ms[511]; Sread holds S(510) transposed
    const float2* Mt = Ms + 511 * 16;
    {   // t1[q][a] = sum_b S[a,b] * Bl[q,b]; thread covers q = h and h+2
        float2 acc0 = make_float2(0,0), acc1 = acc0;
        for (int b = 0; b < 128; ++b) {
            float2 s = Sread[b * 128 + a];
            float2 bl0 = make_float2(bl_re[h*128 + b],     bl_im[h*128 + b]);
            float2 bl1 = make_float2(bl_re[(h+2)*128 + b], bl_im[(h+2)*128 + b]);
            acc0 = cfma(s, bl0, acc0);
            acc1 = cfma(s, bl1, acc1);
        }
        Clds[h][a]     = acc0;    // reuse Clds as t1[4][128]
        Clds[h + 2][a] = acc1;
    }
    __syncthreads();
    float2 tot = make_float2(0,0);
    for (int pp = 0; pp < 2; ++pp) {
        int p = h + pp * 2;
        float2 tp = make_float2(0,0);
        for (int q = 0; q < 4; ++q) tp = cfma(Mt[p*4 + q], Clds[q][a], tp);
        float2 blv = make_float2(bl_re[p*128 + a], bl_im[p*128 + a]);
        tot = cfmac(blv, tp, tot);
    }
    for (int off = 32; off; off >>= 1) {
        tot.x += __shfl_down(tot.x, off, 64);
        tot.y += __shfl_down(tot.y, off, 64);
    }
    if ((tid & 63) == 0) fred[tid >> 6] = tot;
    __syncthreads();
    if (tid == 0) {
        float2 s = make_float2(0,0);
        for (int w = 0; w < 4; ++w) { s.x += fred[w].x; s.y += fred[w].y; }
        out[0] = s.x;
        if (out_size > 1) out[1] = s.y;
    }
}

// ---------------------------------------------------------------------------
extern "C" void kernel_launch(void* const* d_in, const int* in_sizes, int n_in,
                              void* d_out, int out_size, void* d_ws, size_t ws_size,
                              hipStream_t stream)
{
    const float* a_re  = (const float*)d_in[0];
    const float* a_im  = (const float*)d_in[1];
    const float* b0_re = (const float*)d_in[2];
    const float* b0_im = (const float*)d_in[3];
    const float* bm_re = (const float*)d_in[4];
    const float* bm_im = (const float*)d_in[5];
    const float* bl_re = (const float*)d_in[6];
    const float* bl_im = (const float*)d_in[7];
    const int*  tokens = (const int*)d_in[8];

    char* ws = (char*)d_ws;
    float2* Q    = (float2*)(ws);                   // 131072 B
    float2* Ms   = (float2*)(ws + 131072);          //  65536 B
    float2* S0   = (float2*)(ws + 196608);          // 131072 B
    float2* S1b  = (float2*)(ws + 327680);          // 131072 B
    unsigned int* cnt = (unsigned int*)(ws + 458752); // 2048 B

    qr_kernel<<<dim3(1), dim3(512), 0, stream>>>(a_re, a_im, Q);
    ms_kernel<<<dim3(32), dim3(256), 0, stream>>>((const float2*)Q, tokens, Ms, cnt);

    float* outf = (float*)d_out;
    int osz = out_size;
    void* args[] = {
        (void*)&bm_re, (void*)&bm_im, (void*)&b0_re, (void*)&b0_im,
        (void*)&bl_re, (void*)&bl_im,
        (void*)&Ms, (void*)&S0, (void*)&S1b, (void*)&cnt, (void*)&outf, (void*)&osz
    };
    hipLaunchCooperativeKernel((const void*)scan_kernel, dim3(128), dim3(256),
                               args, 0, stream);
}

// Round 3
// 396.811 us; speedup vs baseline: 2.0486x; 1.1637x over previous
//
#include <hip/hip_runtime.h>
#include <hip/hip_cooperative_groups.h>
#include <hip/hip_bf16.h>

// ---------------------------------------------------------------------------
// MPS contraction, N=512 sites, D_PHY=4, D_BOND=128, VOC=1024.
// Faithful computation with EXACT all-zero early exit (state underflows to
// exact 0 after ~19 sites; site map is linear, so remaining sites stay 0).
// Round-3 changes:
//  * no release/acquire fences (no buffer_wbl2 / L2-invalidate per site):
//    S exchanged via agent-scope RELAXED atomic load/store (sc0+sc1 bypass),
//    everything else stays normally cached and L2 stays warm across sites.
//  * 512 threads/wg (2 waves/SIMD) for latency hiding.
//  * register-prefetch of next site's C-step B values under current compute.
// ---------------------------------------------------------------------------

__device__ __forceinline__ float2 cfma(float2 a, float2 b, float2 acc) {
    acc.x = fmaf(a.x, b.x, fmaf(-a.y, b.y, acc.x));
    acc.y = fmaf(a.x, b.y, fmaf( a.y, b.x, acc.y));
    return acc;
}
__device__ __forceinline__ float2 cfmac(float2 a, float2 b, float2 acc) {
    // acc + conj(a)*b
    acc.x = fmaf(a.x, b.x, fmaf( a.y, b.y, acc.x));
    acc.y = fmaf(a.x, b.y, fmaf(-a.y, b.x, acc.y));
    return acc;
}

// coherent (cache-bypassing) 8-byte load/store for the S exchange
__device__ __forceinline__ float2 ld_coh(const float2* p) {
    union { unsigned long long u; float2 f; } cv;
    cv.u = __hip_atomic_load((const unsigned long long*)p,
                             __ATOMIC_RELAXED, __HIP_MEMORY_SCOPE_AGENT);
    return cv.f;
}
__device__ __forceinline__ void st_coh(float2* p, float2 x) {
    union { unsigned long long u; float2 f; } cv;
    cv.f = x;
    __hip_atomic_store((unsigned long long*)p, cv.u,
                       __ATOMIC_RELAXED, __HIP_MEMORY_SCOPE_AGENT);
}

__device__ __forceinline__ double2 d2mul(double2 a, double2 b) {
    return make_double2(a.x*b.x - a.y*b.y, a.x*b.y + a.y*b.x);
}
__device__ __forceinline__ double2 d2conj(double2 a) { return make_double2(a.x, -a.y); }

// block reduction over 512 threads (8 waves), deterministic
__device__ double2 qr_blk_red(double2 v, double2* red) {
    for (int off = 32; off; off >>= 1) {
        v.x += __shfl_down(v.x, off, 64);
        v.y += __shfl_down(v.y, off, 64);
    }
    const int wid = threadIdx.x >> 6, lane = threadIdx.x & 63;
    __syncthreads();
    if (lane == 0) red[wid] = v;
    __syncthreads();
    double2 r = make_double2(0.0, 0.0);
    for (int w = 0; w < 8; ++w) { r.x += red[w].x; r.y += red[w].y; }
    return r;
}

// ---------------------------------------------------------------------------
// Kernel 1: Householder QR of A (4096 x 4 complex), LAPACK clarfg/cungqr
// convention (beta real, sign rule pins the column phases M depends on).
// ---------------------------------------------------------------------------
__global__ __launch_bounds__(512) void qr_kernel(const float* __restrict__ a_re,
                                                 const float* __restrict__ a_im,
                                                 float2* __restrict__ Q)
{
    const int t = threadIdx.x;
    __shared__ double2 red[8];
    __shared__ double2 bc;

    float2 a[8][4];
    for (int i = 0; i < 8; ++i) {
        int r = t + 512 * i;
        for (int j = 0; j < 4; ++j)
            a[i][j] = make_float2(a_re[r*4 + j], a_im[r*4 + j]);
    }
    double2 tau[4];

    for (int k = 0; k < 4; ++k) {
        if (t == k) bc = make_double2((double)a[0][k].x, (double)a[0][k].y);
        __syncthreads();
        const double ar = bc.x, ai = bc.y;

        double xn = 0.0;
        for (int i = 0; i < 8; ++i) {
            int r = t + 512 * i;
            if (r > k) xn += (double)a[i][k].x * a[i][k].x + (double)a[i][k].y * a[i][k].y;
        }
        xn = qr_blk_red(make_double2(xn, 0.0), red).x;

        double2 tk, scale;
        if (xn == 0.0 && ai == 0.0) {
            tk = make_double2(0.0, 0.0);
            scale = make_double2(0.0, 0.0);
        } else {
            double nrm = sqrt(ar*ar + ai*ai + xn);
            double beta = (ar >= 0.0) ? -nrm : nrm;       // clarfg sign rule
            tk = make_double2((beta - ar) / beta, -ai / beta);
            double dr = ar - beta, di = ai;
            double dd = dr*dr + di*di;
            scale = make_double2(dr / dd, -di / dd);      // 1/(alpha-beta)
        }
        tau[k] = tk;

        for (int i = 0; i < 8; ++i) {
            int r = t + 512 * i;
            if (r == k) a[i][k] = make_float2(1.f, 0.f);
            else if (r > k) {
                double2 v = d2mul(make_double2(a[i][k].x, a[i][k].y), scale);
                a[i][k] = make_float2((float)v.x, (float)v.y);
            } else a[i][k] = make_float2(0.f, 0.f);
        }
        __syncthreads();

        for (int j = k + 1; j < 4; ++j) {
            double2 w = make_double2(0.0, 0.0);
            for (int i = 0; i < 8; ++i) {
                double2 vv = make_double2(a[i][k].x, a[i][k].y);
                double2 aa = make_double2(a[i][j].x, a[i][j].y);
                double2 m = d2mul(d2conj(vv), aa);
                w.x += m.x; w.y += m.y;
            }
            w = qr_blk_red(w, red);
            double2 cw = d2mul(d2conj(tk), w);
            for (int i = 0; i < 8; ++i) {
                double2 vv = make_double2(a[i][k].x, a[i][k].y);
                double2 upd = d2mul(cw, vv);
                a[i][j] = make_float2((float)((double)a[i][j].x - upd.x),
                                      (float)((double)a[i][j].y - upd.y));
            }
        }
    }

    float2 q[8][4];
    for (int i = 0; i < 8; ++i) {
        int r = t + 512 * i;
        for (int j = 0; j < 4; ++j)
            q[i][j] = make_float2((r == j) ? 1.f : 0.f, 0.f);
    }
    for (int k = 3; k >= 0; --k) {
        for (int j = k; j < 4; ++j) {
            double2 w = make_double2(0.0, 0.0);
            for (int i = 0; i < 8; ++i) {
                double2 vv = make_double2(a[i][k].x, a[i][k].y);
                double2 qq = make_double2(q[i][j].x, q[i][j].y);
                double2 m = d2mul(d2conj(vv), qq);
                w.x += m.x; w.y += m.y;
            }
            w = qr_blk_red(w, red);
            double2 cw = d2mul(tau[k], w);
            for (int i = 0; i < 8; ++i) {
                double2 vv = make_double2(a[i][k].x, a[i][k].y);
                double2 upd = d2mul(cw, vv);
                q[i][j] = make_float2((float)((double)q[i][j].x - upd.x),
                                      (float)((double)q[i][j].y - upd.y));
            }
        }
    }
    for (int i = 0; i < 8; ++i) {
        int r = t + 512 * i;
        for (int j = 0; j < 4; ++j) Q[r*4 + j] = q[i][j];
    }
}

// ---------------------------------------------------------------------------
// Kernel 2: Ms[t][j][k] = sum_i conj(Q[4v+i,j]) Q[4v+i,k], v=tokens[t];
// zeroes the per-site barrier counters (fresh every replay).
// ---------------------------------------------------------------------------
__global__ __launch_bounds__(256) void ms_kernel(const float2* __restrict__ Q,
                                                 const int* __restrict__ tokens,
                                                 float2* __restrict__ Ms,
                                                 unsigned int* __restrict__ cnt)
{
    const int idx = blockIdx.x * 256 + threadIdx.x;   // 32 blocks -> 8192
    if (idx < 8192) {
        const int ti = idx >> 4, jk = idx & 15, j = jk >> 2, kk = jk & 3;
        const int v = tokens[ti];
        float2 s = make_float2(0.f, 0.f);
        for (int i = 0; i < 4; ++i) {
            float2 q1 = Q[(v*4 + i)*4 + j];
            float2 q2 = Q[(v*4 + i)*4 + kk];
            s.x += q1.x*q2.x + q1.y*q2.y;     // conj(q1)*q2
            s.y += q1.x*q2.y - q1.y*q2.x;
        }
        Ms[idx] = s;
    }
    if (idx < 512) cnt[idx] = 0u;
}

// ---------------------------------------------------------------------------
// Fused grid barrier + liveness, fence-free.
// Prior S stores are write-through (sc0+sc1); __syncthreads() drains vmcnt
// for every wave, so by the time tid 0 adds, this wg's S is globally visible.
// Count field == 128 => word final => liveness bits consistent & uniform.
// Readers use cache-bypassing loads for S, so no acquire invalidate needed.
// ---------------------------------------------------------------------------
#define NWG 128u
__device__ __forceinline__ bool site_barrier(unsigned int* addr,
                                             unsigned* nzw, int* live_lds, int tid)
{
    __syncthreads();                 // drains vmcnt(0) for all waves
    if (tid == 0) {
        unsigned add = 1u | ((nzw[0] | nzw[1]) ? 0x10000u : 0u);
        __hip_atomic_fetch_add(addr, add, __ATOMIC_RELAXED, __HIP_MEMORY_SCOPE_AGENT);
        unsigned v;
        for (;;) {
            v = __hip_atomic_load(addr, __ATOMIC_RELAXED, __HIP_MEMORY_SCOPE_AGENT);
            if ((v & 0xffffu) >= NWG) break;
            __builtin_amdgcn_s_sleep(1);
        }
        *live_lds = (int)(v >> 16);
    }
    __syncthreads();
    return *live_lds != 0;
}

// ---------------------------------------------------------------------------
// Kernel 3: site 0 (folded) + cooperative scan t=1..510 + final site.
// 128 wgs x 512 threads; wg owns output column c (XCD-grouped mapping).
// Per site: C[p][b] = sum_q M[p,q] B[q,b,c]        (prefetched regs -> LDS)
//           U[p][a] = sum_b S[a,b] C[p][b]          (quarter-split b)
//           S'[r,c] = sum_pa conj(B[p,a,r]) U[pa]   (quarter-split pa)
// ---------------------------------------------------------------------------
__global__ __launch_bounds__(512) void scan_kernel(
    const float* __restrict__ bm_re, const float* __restrict__ bm_im,
    const float* __restrict__ b0_re, const float* __restrict__ b0_im,
    const float* __restrict__ bl_re, const float* __restrict__ bl_im,
    const float2* __restrict__ Ms,
    float2* SbufA, float2* SbufB,
    unsigned int* cnt, float* out, int out_size)
{
    const int tid = threadIdx.x;
    const int bid = blockIdx.x;
    const int c = ((bid & 7) << 4) | (bid >> 3);   // same-XCD wgs -> adjacent c

    __shared__ float2 Clds[4][128];
    __shared__ float2 Upart[4][512];
    __shared__ float2 U[512];
    __shared__ float2 red4[4][128];
    __shared__ float2 fred[8];
    __shared__ unsigned nzw[2];
    __shared__ int live_lds;

    const int a = tid & 127;
    const int h = tid >> 7;          // quarter id 0..3 (2 waves per quarter)

    float2* Sread = SbufA;
    float2* Swrite = SbufB;
    bool dead = false;

    // ---- site 0: threads h==0 compute column c of S0 (transposed store)
    if (h == 0) {
        const int r = a;
        float2 brr[4], bcc[4];
        for (int p = 0; p < 4; ++p) {
            brr[p] = make_float2(b0_re[p*128 + r], b0_im[p*128 + r]);
            bcc[p] = make_float2(b0_re[p*128 + c], b0_im[p*128 + c]);
        }
        float2 acc = make_float2(0.f, 0.f);
        for (int p = 0; p < 4; ++p) {
            float2 tp = make_float2(0.f, 0.f);
            for (int q = 0; q < 4; ++q) tp = cfma(Ms[p*4 + q], bcc[q], tp);
            acc = cfmac(brr[p], tp, acc);
        }
        st_coh(&SbufA[c*128 + r], acc);
        int nz = (acc.x != 0.f) || (acc.y != 0.f);
        unsigned long long m = __ballot(nz);
        if ((tid & 63) == 0) nzw[tid >> 6] = (m != 0ULL) ? 1u : 0u;
    }

    // prefetch C-step B values for site t=1
    float prr[4], pri[4];
    {
        const float* brn = bm_re;
        const float* bin = bm_im;
        for (int q = 0; q < 4; ++q) {
            prr[q] = brn[(q*128 + a)*128 + c];
            pri[q] = bin[(q*128 + a)*128 + c];
        }
    }

    if (!site_barrier(&cnt[0], nzw, &live_lds, tid)) dead = true;

    if (!dead) {
        for (int t = 1; t <= 510; ++t) {
            const float2* Mt = Ms + t * 16;
            const float* br = bm_re + (size_t)(t - 1) * 65536;
            const float* bi = bm_im + (size_t)(t - 1) * 65536;

            // ---- C[p][b] from prefetched regs (thread: p=h, b=a)
            {
                float2 acc = make_float2(0.f, 0.f);
                for (int q = 0; q < 4; ++q)
                    acc = cfma(Mt[h*4 + q], make_float2(prr[q], pri[q]), acc);
                Clds[h][a] = acc;
            }
            __syncthreads();

            // ---- issue prefetch for next site (hidden under U/out compute)
            float prr_n[4], pri_n[4];
            if (t < 510) {
                const float* brn = bm_re + (size_t)t * 65536;
                const float* bin = bm_im + (size_t)t * 65536;
                for (int q = 0; q < 4; ++q) {
                    prr_n[q] = brn[(q*128 + a)*128 + c];
                    pri_n[q] = bin[(q*128 + a)*128 + c];
                }
            } else {
                for (int q = 0; q < 4; ++q) { prr_n[q] = 0.f; pri_n[q] = 0.f; }
            }

            // ---- U[p][a] = sum_b S[a,b] C[p][b]; quarter-split b
            float2 u0 = make_float2(0,0), u1 = u0, u2 = u0, u3 = u0;
            #pragma unroll 8
            for (int bb = h * 32; bb < h * 32 + 32; ++bb) {
                float2 s = ld_coh(&Sread[bb * 128 + a]);   // bypass, coalesced
                u0 = cfma(s, Clds[0][bb], u0);
                u1 = cfma(s, Clds[1][bb], u1);
                u2 = cfma(s, Clds[2][bb], u2);
                u3 = cfma(s, Clds[3][bb], u3);
            }
            Upart[h][0*128 + a] = u0;
            Upart[h][1*128 + a] = u1;
            Upart[h][2*128 + a] = u2;
            Upart[h][3*128 + a] = u3;
            __syncthreads();
            {
                float2 x0 = Upart[0][tid], x1 = Upart[1][tid];
                float2 x2 = Upart[2][tid], x3 = Upart[3][tid];
                U[tid] = make_float2(x0.x + x1.x + x2.x + x3.x,
                                     x0.y + x1.y + x2.y + x3.y);
            }
            __syncthreads();

            // ---- S'[r,c] partial: quarter-split pa
            const int r = a;
            float2 o0 = make_float2(0,0), o1 = o0;
            #pragma unroll 4
            for (int pa = h * 128; pa < h * 128 + 128; pa += 2) {
                float2 b1 = make_float2(br[pa*128 + r],     bi[pa*128 + r]);
                float2 b2 = make_float2(br[(pa+1)*128 + r], bi[(pa+1)*128 + r]);
                o0 = cfmac(b1, U[pa],     o0);
                o1 = cfmac(b2, U[pa + 1], o1);
            }
            o0.x += o1.x; o0.y += o1.y;
            red4[h][r] = o0;
            __syncthreads();
            if (h == 0) {
                float2 fin = make_float2(
                    red4[0][r].x + red4[1][r].x + red4[2][r].x + red4[3][r].x,
                    red4[0][r].y + red4[1][r].y + red4[2][r].y + red4[3][r].y);
                st_coh(&Swrite[c * 128 + r], fin);          // write-through
                int nz = (fin.x != 0.f) || (fin.y != 0.f);
                unsigned long long m = __ballot(nz);
                if ((tid & 63) == 0) nzw[tid >> 6] = (m != 0ULL) ? 1u : 0u;
            }
            if (!site_barrier(&cnt[t], nzw, &live_lds, tid)) { dead = true; break; }
            float2* tmp = Sread; Sread = Swrite; Swrite = tmp;
            for (int q = 0; q < 4; ++q) { prr[q] = prr_n[q]; pri[q] = pri_n[q]; }
        }
    }

    if (dead) {
        if (bid == 0 && tid == 0) {
            out[0] = 0.f;
            if (out_size > 1) out[1] = 0.f;
        }
        return;
    }
    if (bid != 0) return;

    // ---- final site: Bl (4,128,1), Ms[511]; Sread holds S(510) transposed
    const float2* Mt = Ms + 511 * 16;
    {   // t1[q=h][a] = sum_b S[a,b] * Bl[q,b]
        float2 acc = make_float2(0,0);
        for (int b = 0; b < 128; ++b) {
            float2 s = ld_coh(&Sread[b * 128 + a]);
            float2 bl = make_float2(bl_re[h*128 + b], bl_im[h*128 + b]);
            acc = cfma(s, bl, acc);
        }
        Clds[h][a] = acc;
    }
    __syncthreads();
    float2 tot;
    {
        float2 tp = make_float2(0,0);
        for (int q = 0; q < 4; ++q) tp = cfma(Mt[h*4 + q], Clds[q][a], tp);
        float2 blv = make_float2(bl_re[h*128 + a], bl_im[h*128 + a]);
        tot = cfmac(blv, tp, make_float2(0,0));
    }
    for (int off = 32; off; off >>= 1) {
        tot.x += __shfl_down(tot.x, off, 64);
        tot.y += __shfl_down(tot.y, off, 64);
    }
    if ((tid & 63) == 0) fred[tid >> 6] = tot;
    __syncthreads();
    if (tid == 0) {
        float2 s = make_float2(0,0);
        for (int w = 0; w < 8; ++w) { s.x += fred[w].x; s.y += fred[w].y; }
        out[0] = s.x;
        if (out_size > 1) out[1] = s.y;
    }
}

// ---------------------------------------------------------------------------
extern "C" void kernel_launch(void* const* d_in, const int* in_sizes, int n_in,
                              void* d_out, int out_size, void* d_ws, size_t ws_size,
                              hipStream_t stream)
{
    const float* a_re  = (const float*)d_in[0];
    const float* a_im  = (const float*)d_in[1];
    const float* b0_re = (const float*)d_in[2];
    const float* b0_im = (const float*)d_in[3];
    const float* bm_re = (const float*)d_in[4];
    const float* bm_im = (const float*)d_in[5];
    const float* bl_re = (const float*)d_in[6];
    const float* bl_im = (const float*)d_in[7];
    const int*  tokens = (const int*)d_in[8];

    char* ws = (char*)d_ws;
    float2* Q    = (float2*)(ws);                   // 131072 B
    float2* Ms   = (float2*)(ws + 131072);          //  65536 B
    float2* S0   = (float2*)(ws + 196608);          // 131072 B
    float2* S1b  = (float2*)(ws + 327680);          // 131072 B
    unsigned int* cnt = (unsigned int*)(ws + 458752); // 2048 B

    qr_kernel<<<dim3(1), dim3(512), 0, stream>>>(a_re, a_im, Q);
    ms_kernel<<<dim3(32), dim3(256), 0, stream>>>((const float2*)Q, tokens, Ms, cnt);

    float* outf = (float*)d_out;
    int osz = out_size;
    void* args[] = {
        (void*)&bm_re, (void*)&bm_im, (void*)&b0_re, (void*)&b0_im,
        (void*)&bl_re, (void*)&bl_im,
        (void*)&Ms, (void*)&S0, (void*)&S1b, (void*)&cnt, (void*)&outf, (void*)&osz
    };
    hipLaunchCooperativeKernel((const void*)scan_kernel, dim3(128), dim3(512),
                               args, 0, stream);
}